// Round 8
// baseline (214.450 us; speedup 1.0000x reference)
//
#include <hip/hip_runtime.h>
#include <stdint.h>

#define N_USER_C  50000
#define N_ITEM_C  100000
#define N_NODES_C 150000
#define EMB_C     64
#define NNZ_C     1200000
#define BATCH_C   4096

#define BKT_SHIFT 9                                   // 512 rows per bucket
#define BKT_ROWS  (1 << BKT_SHIFT)
#define NB        ((N_NODES_C + BKT_ROWS - 1) / BKT_ROWS)   // 293
#define CH        8192                                // edges per binning block
#define NBLK      ((NNZ_C + CH - 1) / CH)             // 147
#define N2        (NB * NBLK)                         // 43071
#define COL_MASK  0x3FFFF                             // 18 bits (N_NODES < 2^18)

typedef _Float16 h16;
typedef _Float16 h16x4 __attribute__((ext_vector_type(4)));
typedef _Float16 h16x8 __attribute__((ext_vector_type(8)));

// ---------------- pass A: per-(block,bucket) histogram of kept edges ----------------
__global__ __launch_bounds__(1024) void k_bin_count(const float* __restrict__ du,
                                                    const int* __restrict__ rows,
                                                    int* __restrict__ cnt2) {
    __shared__ int bk[NB];
    int t = threadIdx.x, blk = blockIdx.x;
    for (int i = t; i < NB; i += 1024) bk[i] = 0;
    __syncthreads();
    int base = blk * CH;
    for (int i = 0; i < CH; i += 1024) {
        int e = base + i + t;
        if (e < NNZ_C && floorf(0.9f + du[e]) != 0.0f)
            atomicAdd(&bk[rows[e] >> BKT_SHIFT], 1);
    }
    __syncthreads();
    for (int i = t; i < NB; i += 1024) cnt2[i * NBLK + blk] = bk[i];
}

// ---------------- pass B1: per-bucket totals ----------------
__global__ __launch_bounds__(256) void k_btot(const int* __restrict__ cnt2,
                                              int* __restrict__ btot) {
    __shared__ int red[256];
    int t = threadIdx.x, i = blockIdx.x;
    red[t] = (t < NBLK) ? cnt2[i * NBLK + t] : 0;
    __syncthreads();
    for (int off = 128; off > 0; off >>= 1) {
        if (t < off) red[t] += red[t + off];
        __syncthreads();
    }
    if (t == 0) btot[i] = red[0];
}

// ---------------- pass B2: scan of 293 bucket totals ----------------
__global__ __launch_bounds__(512) void k_bbase(const int* __restrict__ btot,
                                               int* __restrict__ bbase,
                                               int* __restrict__ base2,
                                               int* __restrict__ row_start) {
    __shared__ int sh[512];
    int t = threadIdx.x;
    int v0 = (t < NB) ? btot[t] : 0;
    sh[t] = v0;
    __syncthreads();
    for (int off = 1; off < 512; off <<= 1) {
        int v = (t >= off) ? sh[t - off] : 0;
        __syncthreads();
        sh[t] += v;
        __syncthreads();
    }
    if (t < NB) bbase[t] = sh[t] - v0;                 // exclusive bucket prefix
    if (t == 511) {
        base2[N2] = sh[511];                           // total kept edges
        row_start[N_NODES_C] = sh[511];                // CSR sentinel
    }
}

// ---------------- pass B3: per-bucket scan of 147 block counts ----------------
__global__ __launch_bounds__(256) void k_bscan(const int* __restrict__ cnt2,
                                               const int* __restrict__ bbase,
                                               int* __restrict__ base2) {
    __shared__ int sh[256];
    int t = threadIdx.x, i = blockIdx.x;
    int v0 = (t < NBLK) ? cnt2[i * NBLK + t] : 0;
    sh[t] = v0;
    __syncthreads();
    for (int off = 1; off < 256; off <<= 1) {
        int v = (t >= off) ? sh[t - off] : 0;
        __syncthreads();
        sh[t] += v;
        __syncthreads();
    }
    if (t < NBLK) base2[i * NBLK + t] = bbase[i] + sh[t] - v0;
}

// ---------------- pass C: bucket-sorted write of packed (rl|col, val) ----------------
__global__ __launch_bounds__(1024) void k_bin_write(const float* __restrict__ av,
                                                    const float* __restrict__ du,
                                                    const int* __restrict__ rows,
                                                    const int* __restrict__ cols,
                                                    const int* __restrict__ base2,
                                                    int2* __restrict__ ev) {
    __shared__ int cur[NB];
    int t = threadIdx.x, blk = blockIdx.x;
    for (int i = t; i < NB; i += 1024) cur[i] = base2[i * NBLK + blk];
    __syncthreads();
    int base = blk * CH;
    for (int i = 0; i < CH; i += 1024) {
        int e = base + i + t;
        if (e < NNZ_C) {
            float m = floorf(0.9f + du[e]);
            if (m != 0.0f) {
                float v = av[e] * m * (float)(1.0 / 0.9);
                int r = rows[e];
                int pos = atomicAdd(&cur[r >> BKT_SHIFT], 1);
                int2 p;
                p.x = ((r & (BKT_ROWS - 1)) << 18) | cols[e];   // rl:9 | col:18
                p.y = __float_as_int(v);
                ev[pos] = p;
            }
        }
    }
}

// ---------------- pass D: per-bucket exact row sort (LDS hist+scan+scatter) ----------------
__global__ __launch_bounds__(256) void k_bucket_sort(const int2* __restrict__ ev,
                                                     const int* __restrict__ base2,
                                                     int2* __restrict__ ep,
                                                     int* __restrict__ row_start) {
    __shared__ int rowcnt[BKT_ROWS];
    __shared__ int cursor[BKT_ROWS];
    __shared__ int tsum[256];
    int t = threadIdx.x, k = blockIdx.x;
    int rowBase = k << BKT_SHIFT;
    int bstart = base2[k * NBLK];
    int bend   = base2[(k + 1) * NBLK];               // k=NB-1 hits base2[N2]=total
    for (int i = t; i < BKT_ROWS; i += 256) rowcnt[i] = 0;
    __syncthreads();
    for (int e = bstart + t; e < bend; e += 256)
        atomicAdd(&rowcnt[((unsigned)ev[e].x) >> 18], 1);
    __syncthreads();
    int a = rowcnt[2 * t], b = rowcnt[2 * t + 1];
    tsum[t] = a + b;
    __syncthreads();
    for (int off = 1; off < 256; off <<= 1) {
        int v = (t >= off) ? tsum[t - off] : 0;
        __syncthreads();
        tsum[t] += v;
        __syncthreads();
    }
    int excl = tsum[t] - (a + b);
    cursor[2 * t]     = excl;
    cursor[2 * t + 1] = excl + a;
    int gr = rowBase + 2 * t;
    if (gr < N_NODES_C)     row_start[gr]     = bstart + excl;
    if (gr + 1 < N_NODES_C) row_start[gr + 1] = bstart + excl + a;
    __syncthreads();
    for (int e = bstart + t; e < bend; e += 256) {
        int2 p = ev[e];
        int rl = ((unsigned)p.x) >> 18;
        int slot = atomicAdd(&cursor[rl], 1);
        p.x &= COL_MASK;                               // strip rl -> clean col
        ep[bstart + slot] = p;
    }
}

// ---------------- one-time f32 tables -> fp16 ego0 ----------------
__global__ __launch_bounds__(256) void k_tohalf(const float4* __restrict__ ue,
                                                const float4* __restrict__ ie,
                                                h16x4* __restrict__ dst) {
    const int totalU = N_USER_C * EMB_C / 4;          // 800k float4s
    const int total  = N_NODES_C * EMB_C / 4;         // 2.4M float4s
    int stride = gridDim.x * blockDim.x;
    for (int i = blockIdx.x * blockDim.x + threadIdx.x; i < total; i += stride) {
        float4 v = (i < totalU) ? ue[i] : ie[i - totalU];
        h16x4 h;
        h[0] = (h16)v.x; h[1] = (h16)v.y; h[2] = (h16)v.z; h[3] = (h16)v.w;
        dst[i] = h;
    }
}

// ---------------- CSR SpMM: one wave per row, 8 direct edge slots x 8 lanes x 16B ----------------
// No shuffles in the loop: 8 lanes share one ep entry (hardware broadcast load).
// Typical deg-7.2 row completes in ONE ep->gather round.
__global__ __launch_bounds__(256) void k_spmm8d(const int* __restrict__ rs,
                                                const int2* __restrict__ ep,
                                                const h16x8* __restrict__ ego,
                                                h16x8* __restrict__ nxt,
                                                const int* __restrict__ flag) {
    int wid  = (blockIdx.x * blockDim.x + threadIdx.x) >> 6;   // one wave per row
    int lane = threadIdx.x & 63;
    if (wid >= N_NODES_C) return;
    if (flag && flag[wid] == 0) return;                // wave-uniform early exit
    int start = rs[wid];
    int end   = rs[wid + 1];
    int slot = lane >> 3;        // edge slot 0..7
    int q    = lane & 7;         // h16x8 segment within the 128B row
    float acc[8] = {0.f, 0.f, 0.f, 0.f, 0.f, 0.f, 0.f, 0.f};
    #pragma unroll 2
    for (int it = start + slot; it < end; it += 8) {
        long long raw = __builtin_nontemporal_load((const long long*)(ep + it));
        int   c = (int)(raw & 0xFFFFFFFFLL);
        float v = __int_as_float((int)(raw >> 32));
        h16x8 g = ego[((int64_t)(c << 3)) + q];        // 128B line per slot
        #pragma unroll
        for (int i = 0; i < 8; ++i) acc[i] += v * (float)g[i];
    }
    #pragma unroll
    for (int m = 8; m <= 32; m <<= 1) {
        #pragma unroll
        for (int i = 0; i < 8; ++i) acc[i] += __shfl_xor(acc[i], m);
    }
    if (lane < 8) {              // slot 0 holds the full sums
        h16x8 h;
        #pragma unroll
        for (int i = 0; i < 8; ++i) h[i] = (h16)acc[i];
        nxt[(int64_t)wid * 8 + q] = h;
    }
}

// ---------------- flag rows whose hop-3 value is needed ----------------
__global__ __launch_bounds__(256) void k_flags(const int* __restrict__ rs,
                                               const int2* __restrict__ ep,
                                               int* __restrict__ flag,
                                               const int* __restrict__ users,
                                               const int* __restrict__ pos,
                                               const int* __restrict__ neg,
                                               const int* __restrict__ ua,
                                               const int* __restrict__ pa,
                                               const int* __restrict__ na,
                                               const int* __restrict__ indexp) {
    int wid  = (blockIdx.x * blockDim.x + threadIdx.x) >> 6;   // batch slot
    int lane = threadIdx.x & 63;
    if (wid >= 3 * BATCH_C) return;
    int s = wid >> 12;
    int j = wid & (BATCH_C - 1);
    int a = (s == 0) ? ua[j] : (s == 1) ? pa[j] : na[j];
    if (a < 3) return;
    int idx0 = indexp[0];
    int row;
    if (s == 0)      row = users[j] + (idx0 ? N_USER_C : 0);
    else if (s == 1) row = pos[j]   + (idx0 ? 0 : N_USER_C);
    else             row = neg[j]   + (idx0 ? 0 : N_USER_C);
    if (lane == 0) flag[row] = 1;                      // hop-3 gathered for a>=3
    if (a == 4) {                                      // cols read by g4 from hop-3
        int start = rs[row], end = rs[row + 1];
        for (int e = start + lane; e < end; e += 64)
            flag[ep[e].x] = 1;                         // benign same-value races
    }
}

// ---------------- fused hop-4: per batch entry with a==4, one wave CSR dot -> out ----------------
__global__ __launch_bounds__(256) void k_spmm_g4(const int* __restrict__ rs,
                                                 const int2* __restrict__ ep,
                                                 const h16x4* __restrict__ ego,
                                                 float* __restrict__ out,
                                                 const int* __restrict__ users,
                                                 const int* __restrict__ pos,
                                                 const int* __restrict__ neg,
                                                 const int* __restrict__ ua,
                                                 const int* __restrict__ pa,
                                                 const int* __restrict__ na,
                                                 const int* __restrict__ indexp) {
    int wid  = (blockIdx.x * blockDim.x + threadIdx.x) >> 6;   // batch slot
    int lane = threadIdx.x & 63;
    if (wid >= 3 * BATCH_C) return;
    int s = wid >> 12;
    int j = wid & (BATCH_C - 1);
    int a = (s == 0) ? ua[j] : (s == 1) ? pa[j] : na[j];
    if (a != 4) return;                                // wave-uniform exit
    int idx0 = indexp[0];
    int row;
    if (s == 0)      row = users[j] + (idx0 ? N_USER_C : 0);
    else if (s == 1) row = pos[j]   + (idx0 ? 0 : N_USER_C);
    else             row = neg[j]   + (idx0 ? 0 : N_USER_C);
    int start = rs[row];
    int end   = rs[row + 1];
    int eo = lane >> 4;
    int l  = lane & 15;
    float4 acc = make_float4(0.f, 0.f, 0.f, 0.f);
    for (int it = start + eo; it < end; it += 4) {
        int2 p = ep[it];
        float v = __int_as_float(p.y);
        h16x4 g = ego[(int64_t)p.x * 16 + l];
        acc.x += v * (float)g[0]; acc.y += v * (float)g[1];
        acc.z += v * (float)g[2]; acc.w += v * (float)g[3];
    }
    acc.x += __shfl_xor(acc.x, 16); acc.y += __shfl_xor(acc.y, 16);
    acc.z += __shfl_xor(acc.z, 16); acc.w += __shfl_xor(acc.w, 16);
    acc.x += __shfl_xor(acc.x, 32); acc.y += __shfl_xor(acc.y, 32);
    acc.z += __shfl_xor(acc.z, 32); acc.w += __shfl_xor(acc.w, 32);
    if (lane < 16) {
        float4* o = (float4*)out + (int64_t)wid * 16 + l;
        float4 cv = *o;
        cv.x += acc.x; cv.y += acc.y; cv.z += acc.z; cv.w += acc.w;
        *o = cv;
    }
}

// ---------------- hop-0 gather from the f32 tables (init) ----------------
__global__ __launch_bounds__(256) void k_gather(const float* __restrict__ srcU,
                                                const float* __restrict__ srcI,
                                                int pivot,
                                                float* __restrict__ out,
                                                const int* __restrict__ users,
                                                const int* __restrict__ pos,
                                                const int* __restrict__ neg,
                                                const int* __restrict__ ua,
                                                const int* __restrict__ pa,
                                                const int* __restrict__ na,
                                                const int* __restrict__ indexp) {
    int t = blockIdx.x * blockDim.x + threadIdx.x;
    if (t >= 3 * BATCH_C * EMB_C) return;
    int d = t & 63;
    int b = t >> 6;            // 0 .. 3*BATCH-1
    int s = b >> 12;           // 0=u, 1=p, 2=n   (BATCH=4096)
    int j = b & (BATCH_C - 1);
    int idx0 = indexp[0];
    int row;
    if (s == 0)      row = users[j] + (idx0 ? N_USER_C : 0);
    else if (s == 1) row = pos[j]   + (idx0 ? 0 : N_USER_C);
    else             row = neg[j]   + (idx0 ? 0 : N_USER_C);
    const float* sp = (row < pivot) ? (srcU + (int64_t)row * EMB_C)
                                    : (srcI + (int64_t)(row - pivot) * EMB_C);
    out[t] = sp[d];
}

// ---------------- fp16 gather-accumulate for hops 1..3 ----------------
__global__ __launch_bounds__(256) void k_gather_h(const h16* __restrict__ src,
                                                  float* __restrict__ out,
                                                  const int* __restrict__ users,
                                                  const int* __restrict__ pos,
                                                  const int* __restrict__ neg,
                                                  const int* __restrict__ ua,
                                                  const int* __restrict__ pa,
                                                  const int* __restrict__ na,
                                                  const int* __restrict__ indexp,
                                                  int hop) {
    int t = blockIdx.x * blockDim.x + threadIdx.x;
    if (t >= 3 * BATCH_C * EMB_C) return;
    int d = t & 63;
    int b = t >> 6;
    int s = b >> 12;
    int j = b & (BATCH_C - 1);
    int idx0 = indexp[0];
    int row, a;
    if (s == 0)      { row = users[j] + (idx0 ? N_USER_C : 0); a = ua[j]; }
    else if (s == 1) { row = pos[j]   + (idx0 ? 0 : N_USER_C); a = pa[j]; }
    else             { row = neg[j]   + (idx0 ? 0 : N_USER_C); a = na[j]; }
    if (hop <= a)
        out[t] += (float)src[(int64_t)row * EMB_C + d];
}

// ---------------- divide by (a+1) ----------------
__global__ __launch_bounds__(256) void k_scale(float* __restrict__ out,
                                               const int* __restrict__ ua,
                                               const int* __restrict__ pa,
                                               const int* __restrict__ na) {
    int t = blockIdx.x * blockDim.x + threadIdx.x;
    if (t >= 3 * BATCH_C * EMB_C) return;
    int b = t >> 6;
    int s = b >> 12;
    int j = b & (BATCH_C - 1);
    int a = (s == 0) ? ua[j] : (s == 1) ? pa[j] : na[j];
    out[t] /= (float)(a + 1);
}

extern "C" void kernel_launch(void* const* d_in, const int* in_sizes, int n_in,
                              void* d_out, int out_size, void* d_ws, size_t ws_size,
                              hipStream_t stream) {
    const float* user_emb = (const float*)d_in[0];
    const float* item_emb = (const float*)d_in[1];
    const float* adj_vals = (const float*)d_in[2];
    const float* drop_u   = (const float*)d_in[3];
    const int*   adj_rows = (const int*)d_in[4];
    const int*   adj_cols = (const int*)d_in[5];
    const int*   users    = (const int*)d_in[6];
    const int*   pos_it   = (const int*)d_in[7];
    const int*   neg_it   = (const int*)d_in[8];
    const int*   u_a      = (const int*)d_in[9];
    const int*   p_a      = (const int*)d_in[10];
    const int*   n_a      = (const int*)d_in[11];
    const int*   indexp   = (const int*)d_in[12];
    float* out = (float*)d_out;

    // workspace layout (~78 MB)
    const size_t egoElems = (size_t)N_NODES_C * EMB_C;       // 9.6M
    h16*   egoH0     = (h16*)d_ws;                           // 19.2 MB
    h16*   bufA      = egoH0 + egoElems;                     // 19.2 MB
    h16*   bufB      = bufA + egoElems;                      // 19.2 MB
    int2*  ep        = (int2*)(bufB + egoElems);             // 9.6 MB (final CSR)
    int2*  ev        = ep + NNZ_C;                           // 9.6 MB (build tmp)
    int*   row_start = (int*)(ev + NNZ_C);                   // 600 KB (+sentinel)
    int*   cnt2      = row_start + N_NODES_C + 1;            // ~172 KB
    int*   base2     = cnt2 + N2 + 1;                        // ~172 KB
    int*   btot      = base2 + N2 + 1;                       // ~1.2 KB
    int*   bbase     = btot + NB + 1;                        // ~1.2 KB
    int*   flags     = bbase + NB + 1;                       // 600 KB

    // ---- CSR build: bucketed counting sort, all randomness L2-confined ----
    k_bin_count<<<NBLK, 1024, 0, stream>>>(drop_u, adj_rows, cnt2);
    k_btot<<<NB, 256, 0, stream>>>(cnt2, btot);
    k_bbase<<<1, 512, 0, stream>>>(btot, bbase, base2, row_start);
    k_bscan<<<NB, 256, 0, stream>>>(cnt2, bbase, base2);
    k_bin_write<<<NBLK, 1024, 0, stream>>>(adj_vals, drop_u, adj_rows, adj_cols,
                                           base2, ev);
    k_bucket_sort<<<NB, 256, 0, stream>>>(ev, base2, ep, row_start);

    // ---- hop-3 need-flags (after CSR is ready) ----
    hipMemsetAsync(flags, 0, N_NODES_C * sizeof(int), stream);
    k_flags<<<(3 * BATCH_C * 64 + 255) / 256, 256, 0, stream>>>(
        row_start, ep, flags, users, pos_it, neg_it, u_a, p_a, n_a, indexp);

    // ---- fp16 ego0 + hop-0 gather ----
    k_tohalf<<<2048, 256, 0, stream>>>((const float4*)user_emb,
                                       (const float4*)item_emb, (h16x4*)egoH0);
    const int GT = 3 * BATCH_C * EMB_C;
    k_gather<<<(GT + 255) / 256, 256, 0, stream>>>(user_emb, item_emb, N_USER_C, out,
                                                   users, pos_it, neg_it,
                                                   u_a, p_a, n_a, indexp);

    // ---- SpMM hops (fp16 ego, direct 8-slot waves); hop 3 flag-pruned; hop 4 fused ----
    const int SPMM_BLOCKS = (N_NODES_C * 64 + 255) / 256;    // one wave per row
    k_spmm8d<<<SPMM_BLOCKS, 256, 0, stream>>>(row_start, ep, (const h16x8*)egoH0,
                                              (h16x8*)bufA, (const int*)nullptr);
    k_gather_h<<<(GT + 255) / 256, 256, 0, stream>>>(bufA, out, users, pos_it, neg_it,
                                                     u_a, p_a, n_a, indexp, 1);
    k_spmm8d<<<SPMM_BLOCKS, 256, 0, stream>>>(row_start, ep, (const h16x8*)bufA,
                                              (h16x8*)bufB, (const int*)nullptr);
    k_gather_h<<<(GT + 255) / 256, 256, 0, stream>>>(bufB, out, users, pos_it, neg_it,
                                                     u_a, p_a, n_a, indexp, 2);
    k_spmm8d<<<SPMM_BLOCKS, 256, 0, stream>>>(row_start, ep, (const h16x8*)bufB,
                                              (h16x8*)bufA, flags);
    k_gather_h<<<(GT + 255) / 256, 256, 0, stream>>>(bufA, out, users, pos_it, neg_it,
                                                     u_a, p_a, n_a, indexp, 3);
    k_spmm_g4<<<(3 * BATCH_C * 64 + 255) / 256, 256, 0, stream>>>(
        row_start, ep, (const h16x4*)bufA, out,
        users, pos_it, neg_it, u_a, p_a, n_a, indexp);

    // ---- final divide by (a+1) ----
    k_scale<<<(GT + 255) / 256, 256, 0, stream>>>(out, u_a, p_a, n_a);
}

// Round 9
// 211.204 us; speedup vs baseline: 1.0154x; 1.0154x over previous
//
#include <hip/hip_runtime.h>
#include <stdint.h>

#define N_USER_C  50000
#define N_ITEM_C  100000
#define N_NODES_C 150000
#define EMB_C     64
#define NNZ_C     1200000
#define BATCH_C   4096

#define BKT_SHIFT 9                                   // 512 rows per bucket
#define BKT_ROWS  (1 << BKT_SHIFT)
#define NB        ((N_NODES_C + BKT_ROWS - 1) / BKT_ROWS)   // 293
#define CH        8192                                // edges per binning block
#define NBLK      ((NNZ_C + CH - 1) / CH)             // 147
#define N2        (NB * NBLK)                         // 43071
#define COL_MASK  0x3FFFF                             // 18 bits (N_NODES < 2^18)

typedef _Float16 h16;
typedef _Float16 h16x4 __attribute__((ext_vector_type(4)));

// ---------------- pass A: per-(block,bucket) histogram of kept edges ----------------
__global__ __launch_bounds__(1024) void k_bin_count(const float* __restrict__ du,
                                                    const int* __restrict__ rows,
                                                    int* __restrict__ cnt2) {
    __shared__ int bk[NB];
    int t = threadIdx.x, blk = blockIdx.x;
    for (int i = t; i < NB; i += 1024) bk[i] = 0;
    __syncthreads();
    int base = blk * CH;
    for (int i = 0; i < CH; i += 1024) {
        int e = base + i + t;
        if (e < NNZ_C && floorf(0.9f + du[e]) != 0.0f)
            atomicAdd(&bk[rows[e] >> BKT_SHIFT], 1);
    }
    __syncthreads();
    for (int i = t; i < NB; i += 1024) cnt2[i * NBLK + blk] = bk[i];
}

// ---------------- pass B1: per-bucket totals ----------------
__global__ __launch_bounds__(256) void k_btot(const int* __restrict__ cnt2,
                                              int* __restrict__ btot) {
    __shared__ int red[256];
    int t = threadIdx.x, i = blockIdx.x;
    red[t] = (t < NBLK) ? cnt2[i * NBLK + t] : 0;
    __syncthreads();
    for (int off = 128; off > 0; off >>= 1) {
        if (t < off) red[t] += red[t + off];
        __syncthreads();
    }
    if (t == 0) btot[i] = red[0];
}

// ---------------- pass B2: scan of 293 bucket totals ----------------
__global__ __launch_bounds__(512) void k_bbase(const int* __restrict__ btot,
                                               int* __restrict__ bbase,
                                               int* __restrict__ base2,
                                               int* __restrict__ row_start) {
    __shared__ int sh[512];
    int t = threadIdx.x;
    int v0 = (t < NB) ? btot[t] : 0;
    sh[t] = v0;
    __syncthreads();
    for (int off = 1; off < 512; off <<= 1) {
        int v = (t >= off) ? sh[t - off] : 0;
        __syncthreads();
        sh[t] += v;
        __syncthreads();
    }
    if (t < NB) bbase[t] = sh[t] - v0;                 // exclusive bucket prefix
    if (t == 511) {
        base2[N2] = sh[511];                           // total kept edges
        row_start[N_NODES_C] = sh[511];                // CSR sentinel
    }
}

// ---------------- pass B3: per-bucket scan of 147 block counts ----------------
__global__ __launch_bounds__(256) void k_bscan(const int* __restrict__ cnt2,
                                               const int* __restrict__ bbase,
                                               int* __restrict__ base2) {
    __shared__ int sh[256];
    int t = threadIdx.x, i = blockIdx.x;
    int v0 = (t < NBLK) ? cnt2[i * NBLK + t] : 0;
    sh[t] = v0;
    __syncthreads();
    for (int off = 1; off < 256; off <<= 1) {
        int v = (t >= off) ? sh[t - off] : 0;
        __syncthreads();
        sh[t] += v;
        __syncthreads();
    }
    if (t < NBLK) base2[i * NBLK + t] = bbase[i] + sh[t] - v0;
}

// ---------------- pass C: bucket-sorted write of packed (rl|col, val) ----------------
__global__ __launch_bounds__(1024) void k_bin_write(const float* __restrict__ av,
                                                    const float* __restrict__ du,
                                                    const int* __restrict__ rows,
                                                    const int* __restrict__ cols,
                                                    const int* __restrict__ base2,
                                                    int2* __restrict__ ev) {
    __shared__ int cur[NB];
    int t = threadIdx.x, blk = blockIdx.x;
    for (int i = t; i < NB; i += 1024) cur[i] = base2[i * NBLK + blk];
    __syncthreads();
    int base = blk * CH;
    for (int i = 0; i < CH; i += 1024) {
        int e = base + i + t;
        if (e < NNZ_C) {
            float m = floorf(0.9f + du[e]);
            if (m != 0.0f) {
                float v = av[e] * m * (float)(1.0 / 0.9);
                int r = rows[e];
                int pos = atomicAdd(&cur[r >> BKT_SHIFT], 1);
                int2 p;
                p.x = ((r & (BKT_ROWS - 1)) << 18) | cols[e];   // rl:9 | col:18
                p.y = __float_as_int(v);
                ev[pos] = p;
            }
        }
    }
}

// ---------------- pass D: per-bucket exact row sort (LDS hist+scan+scatter) ----------------
__global__ __launch_bounds__(256) void k_bucket_sort(const int2* __restrict__ ev,
                                                     const int* __restrict__ base2,
                                                     int2* __restrict__ ep,
                                                     int* __restrict__ row_start) {
    __shared__ int rowcnt[BKT_ROWS];
    __shared__ int cursor[BKT_ROWS];
    __shared__ int tsum[256];
    int t = threadIdx.x, k = blockIdx.x;
    int rowBase = k << BKT_SHIFT;
    int bstart = base2[k * NBLK];
    int bend   = base2[(k + 1) * NBLK];               // k=NB-1 hits base2[N2]=total
    for (int i = t; i < BKT_ROWS; i += 256) rowcnt[i] = 0;
    __syncthreads();
    for (int e = bstart + t; e < bend; e += 256)
        atomicAdd(&rowcnt[((unsigned)ev[e].x) >> 18], 1);
    __syncthreads();
    int a = rowcnt[2 * t], b = rowcnt[2 * t + 1];
    tsum[t] = a + b;
    __syncthreads();
    for (int off = 1; off < 256; off <<= 1) {
        int v = (t >= off) ? tsum[t - off] : 0;
        __syncthreads();
        tsum[t] += v;
        __syncthreads();
    }
    int excl = tsum[t] - (a + b);
    cursor[2 * t]     = excl;
    cursor[2 * t + 1] = excl + a;
    int gr = rowBase + 2 * t;
    if (gr < N_NODES_C)     row_start[gr]     = bstart + excl;
    if (gr + 1 < N_NODES_C) row_start[gr + 1] = bstart + excl + a;
    __syncthreads();
    for (int e = bstart + t; e < bend; e += 256) {
        int2 p = ev[e];
        int rl = ((unsigned)p.x) >> 18;
        int slot = atomicAdd(&cursor[rl], 1);
        p.x &= COL_MASK;                               // strip rl -> clean col
        ep[bstart + slot] = p;
    }
}

// ---------------- one-time f32 tables -> fp16 ego0 ----------------
__global__ __launch_bounds__(256) void k_tohalf(const float4* __restrict__ ue,
                                                const float4* __restrict__ ie,
                                                h16x4* __restrict__ dst) {
    const int totalU = N_USER_C * EMB_C / 4;          // 800k float4s
    const int total  = N_NODES_C * EMB_C / 4;         // 2.4M float4s
    int stride = gridDim.x * blockDim.x;
    for (int i = blockIdx.x * blockDim.x + threadIdx.x; i < total; i += stride) {
        float4 v = (i < totalU) ? ue[i] : ie[i - totalU];
        h16x4 h;
        h[0] = (h16)v.x; h[1] = (h16)v.y; h[2] = (h16)v.z; h[3] = (h16)v.w;
        dst[i] = h;
    }
}

// ---------------- CSR SpMM (fp16): one wave per row, 4 edge slots x 16 lanes x 8B ----------------
// (best measured variant, round 6: 47.6 us full-hop) + optional row-flag early exit
__global__ __launch_bounds__(256) void k_spmm_h(const int* __restrict__ rs,
                                                const int2* __restrict__ ep,
                                                const h16x4* __restrict__ ego,
                                                h16x4* __restrict__ nxt,
                                                const int* __restrict__ flag) {
    int wid  = (blockIdx.x * blockDim.x + threadIdx.x) >> 6;   // one wave per row
    int lane = threadIdx.x & 63;
    if (wid >= N_NODES_C) return;
    if (flag && flag[wid] == 0) return;                // wave-uniform early exit
    int start = rs[wid];
    int end   = rs[wid + 1];
    int eo = lane >> 4;          // edge slot 0..3
    int l  = lane & 15;          // h16x4 index within the 128B row
    float4 acc = make_float4(0.f, 0.f, 0.f, 0.f);
    #pragma unroll 2
    for (int it = start + eo; it < end; it += 4) {
        int2 p = ep[it];
        float v = __int_as_float(p.y);
        h16x4 g = ego[(int64_t)p.x * 16 + l];          // 128B coalesced row gather
        acc.x += v * (float)g[0]; acc.y += v * (float)g[1];
        acc.z += v * (float)g[2]; acc.w += v * (float)g[3];
    }
    acc.x += __shfl_xor(acc.x, 16); acc.y += __shfl_xor(acc.y, 16);
    acc.z += __shfl_xor(acc.z, 16); acc.w += __shfl_xor(acc.w, 16);
    acc.x += __shfl_xor(acc.x, 32); acc.y += __shfl_xor(acc.y, 32);
    acc.z += __shfl_xor(acc.z, 32); acc.w += __shfl_xor(acc.w, 32);
    if (lane < 16) {
        h16x4 h;
        h[0] = (h16)acc.x; h[1] = (h16)acc.y; h[2] = (h16)acc.z; h[3] = (h16)acc.w;
        nxt[(int64_t)wid * 16 + l] = h;
    }
}

// ---------------- flags: hop-3 need (flags3) and batch-a>=2 seed of flags2 ----------------
__global__ __launch_bounds__(256) void k_flags(const int* __restrict__ rs,
                                               const int2* __restrict__ ep,
                                               int* __restrict__ flag3,
                                               int* __restrict__ flag2,
                                               const int* __restrict__ users,
                                               const int* __restrict__ pos,
                                               const int* __restrict__ neg,
                                               const int* __restrict__ ua,
                                               const int* __restrict__ pa,
                                               const int* __restrict__ na,
                                               const int* __restrict__ indexp) {
    int wid  = (blockIdx.x * blockDim.x + threadIdx.x) >> 6;   // batch slot
    int lane = threadIdx.x & 63;
    if (wid >= 3 * BATCH_C) return;
    int s = wid >> 12;
    int j = wid & (BATCH_C - 1);
    int a = (s == 0) ? ua[j] : (s == 1) ? pa[j] : na[j];
    if (a < 2) return;
    int idx0 = indexp[0];
    int row;
    if (s == 0)      row = users[j] + (idx0 ? N_USER_C : 0);
    else if (s == 1) row = pos[j]   + (idx0 ? 0 : N_USER_C);
    else             row = neg[j]   + (idx0 ? 0 : N_USER_C);
    if (lane == 0) {
        flag2[row] = 1;                                // hop-2 gathered for a>=2
        if (a >= 3) flag3[row] = 1;                    // hop-3 gathered for a>=3
    }
    if (a == 4) {                                      // cols read by g4 from hop-3
        int start = rs[row], end = rs[row + 1];
        for (int e = start + lane; e < end; e += 64)
            flag3[ep[e].x] = 1;                        // benign same-value races
    }
}

// ---------------- flags2 |= neighbors of flags3 rows (cols hop-3 will read) ----------------
__global__ __launch_bounds__(256) void k_flags2(const int* __restrict__ rs,
                                                const int2* __restrict__ ep,
                                                const int* __restrict__ flag3,
                                                int* __restrict__ flag2) {
    int wid  = (blockIdx.x * blockDim.x + threadIdx.x) >> 6;   // one wave per node
    int lane = threadIdx.x & 63;
    if (wid >= N_NODES_C) return;
    if (flag3[wid] == 0) return;                       // wave-uniform
    int start = rs[wid], end = rs[wid + 1];
    for (int e = start + lane; e < end; e += 64)
        flag2[ep[e].x] = 1;                            // benign same-value races
}

// ---------------- fused hop-4: per batch entry with a==4, one wave CSR dot -> out ----------------
__global__ __launch_bounds__(256) void k_spmm_g4(const int* __restrict__ rs,
                                                 const int2* __restrict__ ep,
                                                 const h16x4* __restrict__ ego,
                                                 float* __restrict__ out,
                                                 const int* __restrict__ users,
                                                 const int* __restrict__ pos,
                                                 const int* __restrict__ neg,
                                                 const int* __restrict__ ua,
                                                 const int* __restrict__ pa,
                                                 const int* __restrict__ na,
                                                 const int* __restrict__ indexp) {
    int wid  = (blockIdx.x * blockDim.x + threadIdx.x) >> 6;   // batch slot
    int lane = threadIdx.x & 63;
    if (wid >= 3 * BATCH_C) return;
    int s = wid >> 12;
    int j = wid & (BATCH_C - 1);
    int a = (s == 0) ? ua[j] : (s == 1) ? pa[j] : na[j];
    if (a != 4) return;                                // wave-uniform exit
    int idx0 = indexp[0];
    int row;
    if (s == 0)      row = users[j] + (idx0 ? N_USER_C : 0);
    else if (s == 1) row = pos[j]   + (idx0 ? 0 : N_USER_C);
    else             row = neg[j]   + (idx0 ? 0 : N_USER_C);
    int start = rs[row];
    int end   = rs[row + 1];
    int eo = lane >> 4;
    int l  = lane & 15;
    float4 acc = make_float4(0.f, 0.f, 0.f, 0.f);
    for (int it = start + eo; it < end; it += 4) {
        int2 p = ep[it];
        float v = __int_as_float(p.y);
        h16x4 g = ego[(int64_t)p.x * 16 + l];
        acc.x += v * (float)g[0]; acc.y += v * (float)g[1];
        acc.z += v * (float)g[2]; acc.w += v * (float)g[3];
    }
    acc.x += __shfl_xor(acc.x, 16); acc.y += __shfl_xor(acc.y, 16);
    acc.z += __shfl_xor(acc.z, 16); acc.w += __shfl_xor(acc.w, 16);
    acc.x += __shfl_xor(acc.x, 32); acc.y += __shfl_xor(acc.y, 32);
    acc.z += __shfl_xor(acc.z, 32); acc.w += __shfl_xor(acc.w, 32);
    if (lane < 16) {
        float4* o = (float4*)out + (int64_t)wid * 16 + l;
        float4 cv = *o;
        cv.x += acc.x; cv.y += acc.y; cv.z += acc.z; cv.w += acc.w;
        *o = cv;
    }
}

// ---------------- hop-0 gather from the f32 tables (init) ----------------
__global__ __launch_bounds__(256) void k_gather(const float* __restrict__ srcU,
                                                const float* __restrict__ srcI,
                                                int pivot,
                                                float* __restrict__ out,
                                                const int* __restrict__ users,
                                                const int* __restrict__ pos,
                                                const int* __restrict__ neg,
                                                const int* __restrict__ ua,
                                                const int* __restrict__ pa,
                                                const int* __restrict__ na,
                                                const int* __restrict__ indexp) {
    int t = blockIdx.x * blockDim.x + threadIdx.x;
    if (t >= 3 * BATCH_C * EMB_C) return;
    int d = t & 63;
    int b = t >> 6;            // 0 .. 3*BATCH-1
    int s = b >> 12;           // 0=u, 1=p, 2=n   (BATCH=4096)
    int j = b & (BATCH_C - 1);
    int idx0 = indexp[0];
    int row;
    if (s == 0)      row = users[j] + (idx0 ? N_USER_C : 0);
    else if (s == 1) row = pos[j]   + (idx0 ? 0 : N_USER_C);
    else             row = neg[j]   + (idx0 ? 0 : N_USER_C);
    const float* sp = (row < pivot) ? (srcU + (int64_t)row * EMB_C)
                                    : (srcI + (int64_t)(row - pivot) * EMB_C);
    out[t] = sp[d];
}

// ---------------- fp16 gather-accumulate for hops 1..3 ----------------
__global__ __launch_bounds__(256) void k_gather_h(const h16* __restrict__ src,
                                                  float* __restrict__ out,
                                                  const int* __restrict__ users,
                                                  const int* __restrict__ pos,
                                                  const int* __restrict__ neg,
                                                  const int* __restrict__ ua,
                                                  const int* __restrict__ pa,
                                                  const int* __restrict__ na,
                                                  const int* __restrict__ indexp,
                                                  int hop) {
    int t = blockIdx.x * blockDim.x + threadIdx.x;
    if (t >= 3 * BATCH_C * EMB_C) return;
    int d = t & 63;
    int b = t >> 6;
    int s = b >> 12;
    int j = b & (BATCH_C - 1);
    int idx0 = indexp[0];
    int row, a;
    if (s == 0)      { row = users[j] + (idx0 ? N_USER_C : 0); a = ua[j]; }
    else if (s == 1) { row = pos[j]   + (idx0 ? 0 : N_USER_C); a = pa[j]; }
    else             { row = neg[j]   + (idx0 ? 0 : N_USER_C); a = na[j]; }
    if (hop <= a)
        out[t] += (float)src[(int64_t)row * EMB_C + d];
}

// ---------------- divide by (a+1) ----------------
__global__ __launch_bounds__(256) void k_scale(float* __restrict__ out,
                                               const int* __restrict__ ua,
                                               const int* __restrict__ pa,
                                               const int* __restrict__ na) {
    int t = blockIdx.x * blockDim.x + threadIdx.x;
    if (t >= 3 * BATCH_C * EMB_C) return;
    int b = t >> 6;
    int s = b >> 12;
    int j = b & (BATCH_C - 1);
    int a = (s == 0) ? ua[j] : (s == 1) ? pa[j] : na[j];
    out[t] /= (float)(a + 1);
}

extern "C" void kernel_launch(void* const* d_in, const int* in_sizes, int n_in,
                              void* d_out, int out_size, void* d_ws, size_t ws_size,
                              hipStream_t stream) {
    const float* user_emb = (const float*)d_in[0];
    const float* item_emb = (const float*)d_in[1];
    const float* adj_vals = (const float*)d_in[2];
    const float* drop_u   = (const float*)d_in[3];
    const int*   adj_rows = (const int*)d_in[4];
    const int*   adj_cols = (const int*)d_in[5];
    const int*   users    = (const int*)d_in[6];
    const int*   pos_it   = (const int*)d_in[7];
    const int*   neg_it   = (const int*)d_in[8];
    const int*   u_a      = (const int*)d_in[9];
    const int*   p_a      = (const int*)d_in[10];
    const int*   n_a      = (const int*)d_in[11];
    const int*   indexp   = (const int*)d_in[12];
    float* out = (float*)d_out;

    // workspace layout (~79 MB)
    const size_t egoElems = (size_t)N_NODES_C * EMB_C;       // 9.6M
    h16*   egoH0     = (h16*)d_ws;                           // 19.2 MB
    h16*   bufA      = egoH0 + egoElems;                     // 19.2 MB
    h16*   bufB      = bufA + egoElems;                      // 19.2 MB
    int2*  ep        = (int2*)(bufB + egoElems);             // 9.6 MB (final CSR)
    int2*  ev        = ep + NNZ_C;                           // 9.6 MB (build tmp)
    int*   row_start = (int*)(ev + NNZ_C);                   // 600 KB (+sentinel)
    int*   cnt2      = row_start + N_NODES_C + 1;            // ~172 KB
    int*   base2     = cnt2 + N2 + 1;                        // ~172 KB
    int*   btot      = base2 + N2 + 1;                       // ~1.2 KB
    int*   bbase     = btot + NB + 1;                        // ~1.2 KB
    int*   flags3    = bbase + NB + 1;                       // 600 KB
    int*   flags2    = flags3 + N_NODES_C;                   // 600 KB (contiguous w/ flags3)

    // ---- CSR build: bucketed counting sort, all randomness L2-confined ----
    k_bin_count<<<NBLK, 1024, 0, stream>>>(drop_u, adj_rows, cnt2);
    k_btot<<<NB, 256, 0, stream>>>(cnt2, btot);
    k_bbase<<<1, 512, 0, stream>>>(btot, bbase, base2, row_start);
    k_bscan<<<NB, 256, 0, stream>>>(cnt2, bbase, base2);
    k_bin_write<<<NBLK, 1024, 0, stream>>>(adj_vals, drop_u, adj_rows, adj_cols,
                                           base2, ev);
    k_bucket_sort<<<NB, 256, 0, stream>>>(ev, base2, ep, row_start);

    // ---- need-flags for hop-3 (flags3) and hop-2 (flags2) ----
    hipMemsetAsync(flags3, 0, 2 * N_NODES_C * sizeof(int), stream);  // flags3+flags2
    k_flags<<<(3 * BATCH_C * 64 + 255) / 256, 256, 0, stream>>>(
        row_start, ep, flags3, flags2, users, pos_it, neg_it, u_a, p_a, n_a, indexp);
    k_flags2<<<(N_NODES_C * 64 + 255) / 256, 256, 0, stream>>>(
        row_start, ep, flags3, flags2);

    // ---- fp16 ego0 + hop-0 gather ----
    k_tohalf<<<2048, 256, 0, stream>>>((const float4*)user_emb,
                                       (const float4*)item_emb, (h16x4*)egoH0);
    const int GT = 3 * BATCH_C * EMB_C;
    k_gather<<<(GT + 255) / 256, 256, 0, stream>>>(user_emb, item_emb, N_USER_C, out,
                                                   users, pos_it, neg_it,
                                                   u_a, p_a, n_a, indexp);

    // ---- SpMM hops (4-slot fp16); hop2/hop3 flag-pruned; hop 4 fused ----
    const int SPMM_BLOCKS = (N_NODES_C * 64 + 255) / 256;    // one wave per row
    k_spmm_h<<<SPMM_BLOCKS, 256, 0, stream>>>(row_start, ep, (const h16x4*)egoH0,
                                              (h16x4*)bufA, (const int*)nullptr);
    k_gather_h<<<(GT + 255) / 256, 256, 0, stream>>>(bufA, out, users, pos_it, neg_it,
                                                     u_a, p_a, n_a, indexp, 1);
    k_spmm_h<<<SPMM_BLOCKS, 256, 0, stream>>>(row_start, ep, (const h16x4*)bufA,
                                              (h16x4*)bufB, flags2);
    k_gather_h<<<(GT + 255) / 256, 256, 0, stream>>>(bufB, out, users, pos_it, neg_it,
                                                     u_a, p_a, n_a, indexp, 2);
    k_spmm_h<<<SPMM_BLOCKS, 256, 0, stream>>>(row_start, ep, (const h16x4*)bufB,
                                              (h16x4*)bufA, flags3);
    k_gather_h<<<(GT + 255) / 256, 256, 0, stream>>>(bufA, out, users, pos_it, neg_it,
                                                     u_a, p_a, n_a, indexp, 3);
    k_spmm_g4<<<(3 * BATCH_C * 64 + 255) / 256, 256, 0, stream>>>(
        row_start, ep, (const h16x4*)bufA, out,
        users, pos_it, neg_it, u_a, p_a, n_a, indexp);

    // ---- final divide by (a+1) ----
    k_scale<<<(GT + 255) / 256, 256, 0, stream>>>(out, u_a, p_a, n_a);
}

// Round 10
// 194.117 us; speedup vs baseline: 1.1047x; 1.0880x over previous
//
#include <hip/hip_runtime.h>
#include <stdint.h>

#define N_USER_C  50000
#define N_ITEM_C  100000
#define N_NODES_C 150000
#define EMB_C     64
#define NNZ_C     1200000
#define BATCH_C   4096

#define BKT_SHIFT 9                                   // 512 rows per bucket
#define BKT_ROWS  (1 << BKT_SHIFT)
#define NB        ((N_NODES_C + BKT_ROWS - 1) / BKT_ROWS)   // 293
#define CH        8192                                // edges per binning block
#define NBLK      ((NNZ_C + CH - 1) / CH)             // 147
#define N2        (NB * NBLK)                         // 43071
#define COL_MASK  0x3FFFF                             // 18 bits (N_NODES < 2^18)

#define SPMM_B    37500                               // 150000 waves / 4 per block
#define GB        3072                                // 786432 threads / 256
#define THB       2048                                // tohalf stride blocks

typedef _Float16 h16;
typedef _Float16 h16x4 __attribute__((ext_vector_type(4)));

// ---------------- pass A: per-(block,bucket) histogram + flag zeroing ----------------
__global__ __launch_bounds__(1024) void k_bin_count(const float* __restrict__ du,
                                                    const int* __restrict__ rows,
                                                    int* __restrict__ cnt2,
                                                    int* __restrict__ flagz) {
    __shared__ int bk[NB];
    int t = threadIdx.x, blk = blockIdx.x;
    // fold: zero flags3+flags2 (2*N_NODES ints) while we're here
    for (int i = blk * 1024 + t; i < 2 * N_NODES_C; i += NBLK * 1024) flagz[i] = 0;
    for (int i = t; i < NB; i += 1024) bk[i] = 0;
    __syncthreads();
    int base = blk * CH;
    for (int i = 0; i < CH; i += 1024) {
        int e = base + i + t;
        if (e < NNZ_C && floorf(0.9f + du[e]) != 0.0f)
            atomicAdd(&bk[rows[e] >> BKT_SHIFT], 1);
    }
    __syncthreads();
    for (int i = t; i < NB; i += 1024) cnt2[i * NBLK + blk] = bk[i];
}

// ---------------- pass B: bucket totals (serial per thread) + scan of 293 ----------------
__global__ __launch_bounds__(512) void k_bbase(const int* __restrict__ cnt2,
                                               int* __restrict__ bbase,
                                               int* __restrict__ base2,
                                               int* __restrict__ row_start) {
    __shared__ int sh[512];
    int t = threadIdx.x;
    int s = 0;
    if (t < NB) {
        const int* p = cnt2 + t * NBLK;
        for (int i = 0; i < NBLK; ++i) s += p[i];    // independent loads, pipelined
    }
    sh[t] = s;
    __syncthreads();
    for (int off = 1; off < 512; off <<= 1) {
        int v = (t >= off) ? sh[t - off] : 0;
        __syncthreads();
        sh[t] += v;
        __syncthreads();
    }
    if (t < NB) bbase[t] = sh[t] - s;                 // exclusive bucket prefix
    if (t == 511) {
        base2[N2] = sh[511];                          // total kept edges
        row_start[N_NODES_C] = sh[511];               // CSR sentinel
    }
}

// ---------------- pass B3: per-bucket scan of 147 block counts ----------------
__global__ __launch_bounds__(256) void k_bscan(const int* __restrict__ cnt2,
                                               const int* __restrict__ bbase,
                                               int* __restrict__ base2) {
    __shared__ int sh[256];
    int t = threadIdx.x, i = blockIdx.x;
    int v0 = (t < NBLK) ? cnt2[i * NBLK + t] : 0;
    sh[t] = v0;
    __syncthreads();
    for (int off = 1; off < 256; off <<= 1) {
        int v = (t >= off) ? sh[t - off] : 0;
        __syncthreads();
        sh[t] += v;
        __syncthreads();
    }
    if (t < NBLK) base2[i * NBLK + t] = bbase[i] + sh[t] - v0;
}

// ---------------- pass C: bucket-sorted write of packed (rl|col, val) ----------------
__global__ __launch_bounds__(1024) void k_bin_write(const float* __restrict__ av,
                                                    const float* __restrict__ du,
                                                    const int* __restrict__ rows,
                                                    const int* __restrict__ cols,
                                                    const int* __restrict__ base2,
                                                    int2* __restrict__ ev) {
    __shared__ int cur[NB];
    int t = threadIdx.x, blk = blockIdx.x;
    for (int i = t; i < NB; i += 1024) cur[i] = base2[i * NBLK + blk];
    __syncthreads();
    int base = blk * CH;
    for (int i = 0; i < CH; i += 1024) {
        int e = base + i + t;
        if (e < NNZ_C) {
            float m = floorf(0.9f + du[e]);
            if (m != 0.0f) {
                float v = av[e] * m * (float)(1.0 / 0.9);
                int r = rows[e];
                int pos = atomicAdd(&cur[r >> BKT_SHIFT], 1);
                int2 p;
                p.x = ((r & (BKT_ROWS - 1)) << 18) | cols[e];   // rl:9 | col:18
                p.y = __float_as_int(v);
                ev[pos] = p;
            }
        }
    }
}

// ---------------- pass D: per-bucket exact row sort (LDS hist+scan+scatter) ----------------
__global__ __launch_bounds__(256) void k_bucket_sort(const int2* __restrict__ ev,
                                                     const int* __restrict__ base2,
                                                     int2* __restrict__ ep,
                                                     int* __restrict__ row_start) {
    __shared__ int rowcnt[BKT_ROWS];
    __shared__ int cursor[BKT_ROWS];
    __shared__ int tsum[256];
    int t = threadIdx.x, k = blockIdx.x;
    int rowBase = k << BKT_SHIFT;
    int bstart = base2[k * NBLK];
    int bend   = base2[(k + 1) * NBLK];               // k=NB-1 hits base2[N2]=total
    for (int i = t; i < BKT_ROWS; i += 256) rowcnt[i] = 0;
    __syncthreads();
    for (int e = bstart + t; e < bend; e += 256)
        atomicAdd(&rowcnt[((unsigned)ev[e].x) >> 18], 1);
    __syncthreads();
    int a = rowcnt[2 * t], b = rowcnt[2 * t + 1];
    tsum[t] = a + b;
    __syncthreads();
    for (int off = 1; off < 256; off <<= 1) {
        int v = (t >= off) ? tsum[t - off] : 0;
        __syncthreads();
        tsum[t] += v;
        __syncthreads();
    }
    int excl = tsum[t] - (a + b);
    cursor[2 * t]     = excl;
    cursor[2 * t + 1] = excl + a;
    int gr = rowBase + 2 * t;
    if (gr < N_NODES_C)     row_start[gr]     = bstart + excl;
    if (gr + 1 < N_NODES_C) row_start[gr + 1] = bstart + excl + a;
    __syncthreads();
    for (int e = bstart + t; e < bend; e += 256) {
        int2 p = ev[e];
        int rl = ((unsigned)p.x) >> 18;
        int slot = atomicAdd(&cursor[rl], 1);
        p.x &= COL_MASK;                               // strip rl -> clean col
        ep[bstart + slot] = p;
    }
}

// ---------------- shared device helpers ----------------
__device__ __forceinline__ void batch_row_a(int wid, int idx0,
                                            const int* __restrict__ users,
                                            const int* __restrict__ pos,
                                            const int* __restrict__ neg,
                                            const int* __restrict__ ua,
                                            const int* __restrict__ pa,
                                            const int* __restrict__ na,
                                            int& row, int& a) {
    int s = wid >> 12;
    int j = wid & (BATCH_C - 1);
    if (s == 0)      { row = users[j] + (idx0 ? N_USER_C : 0); a = ua[j]; }
    else if (s == 1) { row = pos[j]   + (idx0 ? 0 : N_USER_C); a = pa[j]; }
    else             { row = neg[j]   + (idx0 ? 0 : N_USER_C); a = na[j]; }
}

__device__ __forceinline__ void spmm_row_body(int wid, int lane,
                                              const int* __restrict__ rs,
                                              const int2* __restrict__ ep,
                                              const h16x4* __restrict__ ego,
                                              h16x4* __restrict__ nxt,
                                              const int* __restrict__ flag) {
    if (wid >= N_NODES_C) return;
    if (flag && flag[wid] == 0) return;                // wave-uniform early exit
    int start = rs[wid];
    int end   = rs[wid + 1];
    int eo = lane >> 4;          // edge slot 0..3
    int l  = lane & 15;          // h16x4 index within the 128B row
    float4 acc = make_float4(0.f, 0.f, 0.f, 0.f);
    #pragma unroll 2
    for (int it = start + eo; it < end; it += 4) {
        int2 p = ep[it];
        float v = __int_as_float(p.y);
        h16x4 g = ego[(int64_t)p.x * 16 + l];          // 128B coalesced row gather
        acc.x += v * (float)g[0]; acc.y += v * (float)g[1];
        acc.z += v * (float)g[2]; acc.w += v * (float)g[3];
    }
    acc.x += __shfl_xor(acc.x, 16); acc.y += __shfl_xor(acc.y, 16);
    acc.z += __shfl_xor(acc.z, 16); acc.w += __shfl_xor(acc.w, 16);
    acc.x += __shfl_xor(acc.x, 32); acc.y += __shfl_xor(acc.y, 32);
    acc.z += __shfl_xor(acc.z, 32); acc.w += __shfl_xor(acc.w, 32);
    if (lane < 16) {
        h16x4 h;
        h[0] = (h16)acc.x; h[1] = (h16)acc.y; h[2] = (h16)acc.z; h[3] = (h16)acc.w;
        nxt[(int64_t)wid * 16 + l] = h;
    }
}

// gather-accumulate hop h, pre-scaled by 1/(a+1)
__device__ __forceinline__ void gather_body(const h16* __restrict__ src,
                                            float* __restrict__ out, int t, int hop,
                                            int idx0,
                                            const int* __restrict__ users,
                                            const int* __restrict__ pos,
                                            const int* __restrict__ neg,
                                            const int* __restrict__ ua,
                                            const int* __restrict__ pa,
                                            const int* __restrict__ na) {
    int d = t & 63;
    int b = t >> 6;
    int row, a;
    batch_row_a(b, idx0, users, pos, neg, ua, pa, na, row, a);
    if (hop <= a)
        out[t] += (float)src[(int64_t)row * EMB_C + d] / (float)(a + 1);
}

// ---------------- fused: fp16 conversion + pre-scaled hop-0 init ----------------
__global__ __launch_bounds__(256) void k_prep(const float* __restrict__ ue,
                                              const float* __restrict__ ie,
                                              h16x4* __restrict__ dst,
                                              float* __restrict__ out,
                                              const int* __restrict__ users,
                                              const int* __restrict__ pos,
                                              const int* __restrict__ neg,
                                              const int* __restrict__ ua,
                                              const int* __restrict__ pa,
                                              const int* __restrict__ na,
                                              const int* __restrict__ indexp) {
    if (blockIdx.x < GB) {                             // hop-0 init (all of out)
        int t = blockIdx.x * 256 + threadIdx.x;
        int d = t & 63;
        int b = t >> 6;
        int row, a;
        batch_row_a(b, indexp[0], users, pos, neg, ua, pa, na, row, a);
        const float* sp = (row < N_USER_C) ? (ue + (int64_t)row * EMB_C)
                                           : (ie + (int64_t)(row - N_USER_C) * EMB_C);
        out[t] = sp[d] / (float)(a + 1);
    } else {                                           // f32 tables -> fp16 ego0
        const int totalU = N_USER_C * EMB_C / 4;
        const int total  = N_NODES_C * EMB_C / 4;
        const int stride = THB * 256;
        const float4* uev = (const float4*)ue;
        const float4* iev = (const float4*)ie;
        for (int i = (blockIdx.x - GB) * 256 + threadIdx.x; i < total; i += stride) {
            float4 v = (i < totalU) ? uev[i] : iev[i - totalU];
            h16x4 h;
            h[0] = (h16)v.x; h[1] = (h16)v.y; h[2] = (h16)v.z; h[3] = (h16)v.w;
            dst[i] = h;
        }
    }
}

// ---------------- fused: hop-1 full SpMM + need-flag seeding ----------------
__global__ __launch_bounds__(256) void k_spmm1f(const int* __restrict__ rs,
                                                const int2* __restrict__ ep,
                                                const h16x4* __restrict__ ego,
                                                h16x4* __restrict__ nxt,
                                                int* __restrict__ flag3,
                                                int* __restrict__ flag2,
                                                const int* __restrict__ users,
                                                const int* __restrict__ pos,
                                                const int* __restrict__ neg,
                                                const int* __restrict__ ua,
                                                const int* __restrict__ pa,
                                                const int* __restrict__ na,
                                                const int* __restrict__ indexp) {
    int lane = threadIdx.x & 63;
    if (blockIdx.x < SPMM_B) {
        int wid = (blockIdx.x * 256 + threadIdx.x) >> 6;
        spmm_row_body(wid, lane, rs, ep, ego, nxt, (const int*)nullptr);
    } else {
        int wid = ((blockIdx.x - SPMM_B) * 256 + threadIdx.x) >> 6;
        if (wid >= 3 * BATCH_C) return;
        int row, a;
        batch_row_a(wid, indexp[0], users, pos, neg, ua, pa, na, row, a);
        if (a < 2) return;
        if (lane == 0) {
            flag2[row] = 1;                            // hop-2 gathered for a>=2
            if (a >= 3) flag3[row] = 1;                // hop-3 gathered for a>=3
        }
        if (a == 4) {                                  // cols read by hop-4 dot
            int start = rs[row], end = rs[row + 1];
            for (int e = start + lane; e < end; e += 64)
                flag3[ep[e].x] = 1;                    // benign same-value races
        }
    }
}

// ---------------- fused: flags2 |= N(flags3)  +  hop-1 gather ----------------
__global__ __launch_bounds__(256) void k_fg1(const int* __restrict__ rs,
                                             const int2* __restrict__ ep,
                                             const int* __restrict__ flag3,
                                             int* __restrict__ flag2,
                                             const h16* __restrict__ src,
                                             float* __restrict__ out,
                                             const int* __restrict__ users,
                                             const int* __restrict__ pos,
                                             const int* __restrict__ neg,
                                             const int* __restrict__ ua,
                                             const int* __restrict__ pa,
                                             const int* __restrict__ na,
                                             const int* __restrict__ indexp) {
    if (blockIdx.x < SPMM_B) {                         // flags2 expansion
        int wid  = (blockIdx.x * 256 + threadIdx.x) >> 6;
        int lane = threadIdx.x & 63;
        if (wid >= N_NODES_C || flag3[wid] == 0) return;
        int start = rs[wid], end = rs[wid + 1];
        for (int e = start + lane; e < end; e += 64)
            flag2[ep[e].x] = 1;                        // benign same-value races
    } else {                                           // hop-1 gather
        int t = (blockIdx.x - SPMM_B) * 256 + threadIdx.x;
        gather_body(src, out, t, 1, indexp[0], users, pos, neg, ua, pa, na);
    }
}

// ---------------- hop-2 SpMM (flags2-pruned) ----------------
__global__ __launch_bounds__(256) void k_spmm2(const int* __restrict__ rs,
                                               const int2* __restrict__ ep,
                                               const h16x4* __restrict__ ego,
                                               h16x4* __restrict__ nxt,
                                               const int* __restrict__ flag) {
    int wid  = (blockIdx.x * 256 + threadIdx.x) >> 6;
    int lane = threadIdx.x & 63;
    spmm_row_body(wid, lane, rs, ep, ego, nxt, flag);
}

// ---------------- fused: hop-3 SpMM (flags3) + hop-2 gather ----------------
__global__ __launch_bounds__(256) void k_spmm3g2(const int* __restrict__ rs,
                                                 const int2* __restrict__ ep,
                                                 const h16x4* __restrict__ ego,
                                                 h16x4* __restrict__ nxt,
                                                 const int* __restrict__ flag3,
                                                 const h16* __restrict__ gsrc,
                                                 float* __restrict__ out,
                                                 const int* __restrict__ users,
                                                 const int* __restrict__ pos,
                                                 const int* __restrict__ neg,
                                                 const int* __restrict__ ua,
                                                 const int* __restrict__ pa,
                                                 const int* __restrict__ na,
                                                 const int* __restrict__ indexp) {
    if (blockIdx.x < SPMM_B) {
        int wid  = (blockIdx.x * 256 + threadIdx.x) >> 6;
        int lane = threadIdx.x & 63;
        spmm_row_body(wid, lane, rs, ep, ego, nxt, flag3);
    } else {
        int t = (blockIdx.x - SPMM_B) * 256 + threadIdx.x;
        gather_body(gsrc, out, t, 2, indexp[0], users, pos, neg, ua, pa, na);
    }
}

// ---------------- fused epilogue: hop-3 gather + hop-4 dot, pre-scaled ----------------
__global__ __launch_bounds__(256) void k_g3g4(const int* __restrict__ rs,
                                              const int2* __restrict__ ep,
                                              const h16x4* __restrict__ ego,   // hop-3 values
                                              float* __restrict__ out,
                                              const int* __restrict__ users,
                                              const int* __restrict__ pos,
                                              const int* __restrict__ neg,
                                              const int* __restrict__ ua,
                                              const int* __restrict__ pa,
                                              const int* __restrict__ na,
                                              const int* __restrict__ indexp) {
    int gid  = blockIdx.x * 256 + threadIdx.x;
    int wid  = gid >> 6;                               // batch slot
    int lane = gid & 63;
    if (wid >= 3 * BATCH_C) return;
    int row, a;
    batch_row_a(wid, indexp[0], users, pos, neg, ua, pa, na, row, a);
    if (a < 3) return;                                 // wave-uniform
    float4 acc = make_float4(0.f, 0.f, 0.f, 0.f);
    if (a == 4) {                                      // E4 = (A*E3)[row]
        int start = rs[row], end = rs[row + 1];
        int eo = lane >> 4;
        int l  = lane & 15;
        for (int it = start + eo; it < end; it += 4) {
            int2 p = ep[it];
            float v = __int_as_float(p.y);
            h16x4 g = ego[(int64_t)p.x * 16 + l];
            acc.x += v * (float)g[0]; acc.y += v * (float)g[1];
            acc.z += v * (float)g[2]; acc.w += v * (float)g[3];
        }
        acc.x += __shfl_xor(acc.x, 16); acc.y += __shfl_xor(acc.y, 16);
        acc.z += __shfl_xor(acc.z, 16); acc.w += __shfl_xor(acc.w, 16);
        acc.x += __shfl_xor(acc.x, 32); acc.y += __shfl_xor(acc.y, 32);
        acc.z += __shfl_xor(acc.z, 32); acc.w += __shfl_xor(acc.w, 32);
    }
    if (lane < 16) {                                   // out += (E3 + E4) / (a+1)
        h16x4 g = ego[(int64_t)row * 16 + lane];
        float inv = 1.0f / (float)(a + 1);
        float4* o = (float4*)out + (int64_t)wid * 16 + lane;
        float4 cv = *o;
        cv.x += ((float)g[0] + acc.x) * inv;
        cv.y += ((float)g[1] + acc.y) * inv;
        cv.z += ((float)g[2] + acc.z) * inv;
        cv.w += ((float)g[3] + acc.w) * inv;
        *o = cv;
    }
}

extern "C" void kernel_launch(void* const* d_in, const int* in_sizes, int n_in,
                              void* d_out, int out_size, void* d_ws, size_t ws_size,
                              hipStream_t stream) {
    const float* user_emb = (const float*)d_in[0];
    const float* item_emb = (const float*)d_in[1];
    const float* adj_vals = (const float*)d_in[2];
    const float* drop_u   = (const float*)d_in[3];
    const int*   adj_rows = (const int*)d_in[4];
    const int*   adj_cols = (const int*)d_in[5];
    const int*   users    = (const int*)d_in[6];
    const int*   pos_it   = (const int*)d_in[7];
    const int*   neg_it   = (const int*)d_in[8];
    const int*   u_a      = (const int*)d_in[9];
    const int*   p_a      = (const int*)d_in[10];
    const int*   n_a      = (const int*)d_in[11];
    const int*   indexp   = (const int*)d_in[12];
    float* out = (float*)d_out;

    // workspace layout (~79 MB)
    const size_t egoElems = (size_t)N_NODES_C * EMB_C;       // 9.6M
    h16*   egoH0     = (h16*)d_ws;                           // 19.2 MB
    h16*   bufA      = egoH0 + egoElems;                     // 19.2 MB
    h16*   bufB      = bufA + egoElems;                      // 19.2 MB
    int2*  ep        = (int2*)(bufB + egoElems);             // 9.6 MB (final CSR)
    int2*  ev        = ep + NNZ_C;                           // 9.6 MB (build tmp)
    int*   row_start = (int*)(ev + NNZ_C);                   // 600 KB (+sentinel)
    int*   cnt2      = row_start + N_NODES_C + 1;            // ~172 KB
    int*   base2     = cnt2 + N2 + 1;                        // ~172 KB
    int*   bbase     = base2 + N2 + 1;                       // ~1.2 KB
    int*   flags3    = bbase + NB + 1;                       // 600 KB
    int*   flags2    = flags3 + N_NODES_C;                   // 600 KB (contiguous)

    // ---- CSR build (5 dispatches); flags zeroed inside bin_count ----
    k_bin_count<<<NBLK, 1024, 0, stream>>>(drop_u, adj_rows, cnt2, flags3);
    k_bbase<<<1, 512, 0, stream>>>(cnt2, bbase, base2, row_start);
    k_bscan<<<NB, 256, 0, stream>>>(cnt2, bbase, base2);
    k_bin_write<<<NBLK, 1024, 0, stream>>>(adj_vals, drop_u, adj_rows, adj_cols,
                                           base2, ev);
    k_bucket_sort<<<NB, 256, 0, stream>>>(ev, base2, ep, row_start);

    // ---- fp16 ego0 conversion + pre-scaled hop-0 init (1 dispatch) ----
    k_prep<<<GB + THB, 256, 0, stream>>>(user_emb, item_emb, (h16x4*)egoH0, out,
                                         users, pos_it, neg_it, u_a, p_a, n_a, indexp);

    // ---- hop-1 SpMM + flag seeding (1 dispatch) ----
    k_spmm1f<<<SPMM_B + GB, 256, 0, stream>>>(row_start, ep, (const h16x4*)egoH0,
                                              (h16x4*)bufA, flags3, flags2,
                                              users, pos_it, neg_it, u_a, p_a, n_a, indexp);
    // ---- flags2 expansion + hop-1 gather (1 dispatch) ----
    k_fg1<<<SPMM_B + GB, 256, 0, stream>>>(row_start, ep, flags3, flags2,
                                           bufA, out,
                                           users, pos_it, neg_it, u_a, p_a, n_a, indexp);
    // ---- hop-2 SpMM, flags2-pruned (1 dispatch) ----
    k_spmm2<<<SPMM_B, 256, 0, stream>>>(row_start, ep, (const h16x4*)bufA,
                                        (h16x4*)bufB, flags2);
    // ---- hop-3 SpMM (flags3) + hop-2 gather (1 dispatch) ----
    k_spmm3g2<<<SPMM_B + GB, 256, 0, stream>>>(row_start, ep, (const h16x4*)bufB,
                                               (h16x4*)bufA, flags3, bufB, out,
                                               users, pos_it, neg_it, u_a, p_a, n_a, indexp);
    // ---- hop-3 gather + fused hop-4 dot (1 dispatch) ----
    k_g3g4<<<GB, 256, 0, stream>>>(row_start, ep, (const h16x4*)bufA, out,
                                   users, pos_it, neg_it, u_a, p_a, n_a, indexp);
}